// Round 2
// baseline (1179.669 us; speedup 1.0000x reference)
//
#include <hip/hip_runtime.h>
#include <stdint.h>

#define B_   8
#define T_   1024
#define CIN_ 4096
#define CH_  4096

// ---------------- helpers ----------------

// per-byte nonzero -> 0x01, packed
__device__ __forceinline__ uint32_t bytes_nonzero01(uint32_t w) {
  uint32_t t = (w & 0x7F7F7F7Fu) + 0x7F7F7F7Fu;
  t = (t | w) & 0x80808080u;
  return t >> 7;
}

// load 4 consecutive boolean elements (elements idx4*4 .. idx4*4+3) from a
// buffer whose element size is es (1, 2 or 4 bytes); return packed bytes 0/1.
__device__ __forceinline__ uint32_t load4(const void* base, long idx4, int es) {
  if (es == 1) {
    uint32_t w = ((const uint32_t*)base)[idx4];
    return bytes_nonzero01(w);
  } else if (es == 2) {
    uint32_t w0 = ((const uint32_t*)base)[idx4 * 2];
    uint32_t w1 = ((const uint32_t*)base)[idx4 * 2 + 1];
    uint32_t r = 0;
    r |= ((w0 & 0xFFFFu) != 0u) ? 0x00000001u : 0u;
    r |= ((w0 >> 16)     != 0u) ? 0x00000100u : 0u;
    r |= ((w1 & 0xFFFFu) != 0u) ? 0x00010000u : 0u;
    r |= ((w1 >> 16)     != 0u) ? 0x01000000u : 0u;
    return r;
  } else {
    uint4 w = ((const uint4*)base)[idx4];
    uint32_t r = 0;
    r |= (w.x != 0u) ? 0x00000001u : 0u;
    r |= (w.y != 0u) ? 0x00000100u : 0u;
    r |= (w.z != 0u) ? 0x00010000u : 0u;
    r |= (w.w != 0u) ? 0x01000000u : 0u;
    return r;
  }
}

// pack 4 bytes (each 0/1) into a 4-bit nibble, b0 -> bit0
__device__ __forceinline__ uint32_t nib4(uint32_t w) {
  return (((w & 0x01010101u) * 0x01020408u) >> 24) & 0xFu;
}

// ---------------- kernel 0: encoding detection ----------------
// Classify how the harness encoded the bool arrays. Scans first 4096 u32
// words of z. mode = element size in bytes (1, 2, or 4).
// Round-1 evidence: absmax = float_bits(1.0)-1 => harness uses int32 for bool
// arrays; detect resolves mode=4 via the sW branch. Kept for robustness.
__global__ __launch_bounds__(256) void detect_kernel(const uint32_t* __restrict__ z,
                                                     uint32_t* __restrict__ modep) {
  __shared__ int sB, sH, sW, sL;
  const int n = threadIdx.x;
  if (n == 0) { sB = 1; sH = 1; sW = 1; sL = 0; }
  __syncthreads();
  int okB = 1, okH = 1, okW = 1, low = 0;
  for (int k = 0; k < 16; ++k) {
    uint32_t w = z[n + 256 * k];
    if ((w & 0xFEFEFEFEu) != 0u) okB = 0;                    // bytes in {0,1}?
    uint32_t lo = w & 0xFFFFu, hi = w >> 16;
    if (!((lo == 0u || lo == 0x3F80u) && (hi == 0u || hi == 0x3F80u))) okH = 0;
    if (!(w == 0u || w == 1u)) okW = 0;                      // words in {0,1}?
    if (lo != 0u) low = 1;                                   // f32 has low half 0
  }
  if (!okB) atomicAnd(&sB, 0);
  if (!okH) atomicAnd(&sH, 0);
  if (!okW) atomicAnd(&sW, 0);
  if (low)  atomicOr(&sL, 1);
  __syncthreads();
  if (n == 0) {
    uint32_t mode;
    if (sW)      mode = 4;              // int32 0/1
    else if (sB) mode = 1;              // uint8 bool
    else if (sH) mode = sL ? 2 : 4;     // bf16 : float32
    else         mode = 1;              // fallback (shouldn't happen)
    modep[0] = mode;
  }
}

// ---------------- kernel 1: fan-in index extraction ----------------
// One wave per row; rows 0..4095 = A_input, 4096..8191 = A_hidden.
__global__ __launch_bounds__(256) void extract_kernel(const float* __restrict__ Ain,
                                                      const float* __restrict__ Ah,
                                                      uint32_t* __restrict__ idxin,
                                                      uint32_t* __restrict__ idxh) {
  const int wave = threadIdx.x >> 6;
  const int lane = threadIdx.x & 63;
  const int row  = blockIdx.x * 4 + wave;   // 0..8191
  const float* A;
  uint32_t* outp;
  if (row < 4096) { A = Ain + (long)row * 4096;          outp = idxin + row * 3; }
  else            { A = Ah  + (long)(row - 4096) * 4096; outp = idxh + (row - 4096) * 3; }
  int count = 0;
  for (int it = 0; it < 64; ++it) {
    float v = A[it * 64 + lane];
    unsigned long long m = __ballot(v != 0.0f);
    if (m) {
      if (v != 0.0f) {
        int pos = count + (int)__popcll(m & ((1ull << lane) - 1ull));
        if (pos < 3) outp[pos] = (uint32_t)(it * 64 + lane);
      }
      count += (int)__popcll(m);
      if (count >= 3) break;   // exactly 3 per row; wave-uniform break
    }
  }
}

// ---------------- kernel 2: batch-packed input-OR precompute ----------------
// in_orb byte [t][i] = bit b set iff (z[b,t,c0]|z[b,t,c1]|z[b,t,c2]).
__global__ __launch_bounds__(1024) void inor_kernel(const void* __restrict__ z,
                                                    const uint32_t* __restrict__ idxin,
                                                    const uint32_t* __restrict__ modep,
                                                    uint32_t* __restrict__ in_orb) {
  const int t = blockIdx.x;
  const int n = threadIdx.x;
  const int es = (int)modep[0];
  __shared__ __align__(16) unsigned char zp[4096];   // batch-packed z row
  uint32_t acc = 0;
  for (int b = 0; b < B_; ++b) {
    uint32_t v4 = load4(z, ((long)b * T_ + t) * 1024 + n, es);
    acc |= v4 << b;
  }
  ((uint32_t*)zp)[n] = acc;
  __syncthreads();
  const uint4* ip = (const uint4*)(idxin + n * 12);  // indices for neurons 4n..4n+3
  uint4 q0 = ip[0], q1 = ip[1], q2 = ip[2];
  uint32_t r0 = (uint32_t)zp[q0.x] | zp[q0.y] | zp[q0.z];
  uint32_t r1 = (uint32_t)zp[q0.w] | zp[q1.x] | zp[q1.y];
  uint32_t r2 = (uint32_t)zp[q1.z] | zp[q1.w] | zp[q2.x];
  uint32_t r3 = (uint32_t)zp[q2.y] | zp[q2.z] | zp[q2.w];
  in_orb[t * 1024 + n] = r0 | (r1 << 8) | (r2 << 16) | (r3 << 24);
}

// ---------------- kernel 3: sequential scan (the recurrence) ----------------
// 8 blocks, one per batch. h kept as 4096 bytes in double-buffered LDS.
__global__ __launch_bounds__(1024) void scan_kernel(const uint32_t* __restrict__ in_orb,
                                                    const uint32_t* __restrict__ idxh,
                                                    const void* __restrict__ h0,
                                                    const uint32_t* __restrict__ modep,
                                                    uint32_t* __restrict__ hbits) {
  const int b = blockIdx.x;
  const int n = threadIdx.x;
  const int es = (int)modep[0];
  __shared__ __align__(16) unsigned char hbuf[2][4096];

  // fan-in indices for neurons 4n..4n+3 -> registers (loop-invariant)
  uint32_t d[4][3];
  {
    const uint4* p = (const uint4*)(idxh + n * 12);
    uint4 q0 = p[0], q1 = p[1], q2 = p[2];
    d[0][0] = q0.x; d[0][1] = q0.y; d[0][2] = q0.z;
    d[1][0] = q0.w; d[1][1] = q1.x; d[1][2] = q1.y;
    d[2][0] = q1.z; d[2][1] = q1.w; d[2][2] = q2.x;
    d[3][0] = q2.y; d[3][1] = q2.z; d[3][2] = q2.w;
  }

  // init h(-1) = h0[b]
  ((uint32_t*)hbuf[0])[n] = load4(h0, (long)b * 1024 + n, es);
  __syncthreads();

  int p = 0;
  uint32_t inw = in_orb[n];   // t = 0 (prefetched)
  for (int t = 0; t < T_; ++t) {
    uint32_t inw_next = (t + 1 < T_) ? in_orb[(t + 1) * 1024 + n] : 0u;
    const unsigned char* hc = &hbuf[p][0];
    unsigned char* hn = &hbuf[p ^ 1][0];

    uint32_t mask = (inw >> b) & 0x01010101u;   // input-OR bits for my 4 neurons
    uint32_t out4 = 0;
    if (mask) {  // early-out: ~61% of masks per neuron are 0
      if (mask & 0x00000001u) {
        uint32_t v = (uint32_t)hc[d[0][0]] | hc[d[0][1]] | hc[d[0][2]];
        out4 |= v;
      }
      if (mask & 0x00000100u) {
        uint32_t v = (uint32_t)hc[d[1][0]] | hc[d[1][1]] | hc[d[1][2]];
        out4 |= v << 8;
      }
      if (mask & 0x00010000u) {
        uint32_t v = (uint32_t)hc[d[2][0]] | hc[d[2][1]] | hc[d[2][2]];
        out4 |= v << 16;
      }
      if (mask & 0x01000000u) {
        uint32_t v = (uint32_t)hc[d[3][0]] | hc[d[3][1]] | hc[d[3][2]];
        out4 |= v << 24;
      }
    }
    ((uint32_t*)hn)[n] = out4;   // bytes 0/1
    __syncthreads();

    // pack this step's 4096 h-bytes into 128 bit-words (threads 0..127);
    // safe to read hn concurrently with next step (next step writes hbuf[p]).
    if (n < 128) {
      const uint4* hp = (const uint4*)hn;
      uint4 a = hp[n * 2];
      uint4 c = hp[n * 2 + 1];
      uint32_t wb = nib4(a.x) | (nib4(a.y) << 4) | (nib4(a.z) << 8)  | (nib4(a.w) << 12)
                  | (nib4(c.x) << 16) | (nib4(c.y) << 20) | (nib4(c.z) << 24) | (nib4(c.w) << 28);
      hbits[((long)b * T_ + t) * 128 + n] = wb;
    }
    inw = inw_next;
    p ^= 1;
  }
}

// ---------------- kernel 4: output expansion ----------------
// out[b][t][0..4095] = z as int32 0/1; out[b][t][4096..8191] = h bits as int32.
// (Round-1 post-mortem: harness reads d_out as int32 for bool references.)
__global__ __launch_bounds__(1024) void expand_kernel(const void* __restrict__ z,
                                                      const uint32_t* __restrict__ hbits,
                                                      const uint32_t* __restrict__ modep,
                                                      uint32_t* __restrict__ out) {
  const long bt = blockIdx.x;      // b*T + t
  const int n = threadIdx.x;
  const int es = (int)modep[0];
  __shared__ uint32_t hw[128];
  if (n < 128) hw[n] = hbits[bt * 128 + n];
  uint32_t zv = load4(z, bt * 1024 + n, es);
  __syncthreads();
  uint32_t* o = out + bt * 8192;
  uint4 zf = { zv & 1u, (zv >> 8) & 1u, (zv >> 16) & 1u, (zv >> 24) & 1u };
  ((uint4*)o)[n] = zf;
  uint32_t w = hw[n >> 3];
  uint32_t nb = (w >> ((n & 7) * 4)) & 0xFu;
  uint4 hf = { nb & 1u, (nb >> 1) & 1u, (nb >> 2) & 1u, (nb >> 3) & 1u };
  ((uint4*)(o + 4096))[n] = hf;
}

// ---------------- launch ----------------
extern "C" void kernel_launch(void* const* d_in, const int* in_sizes, int n_in,
                              void* d_out, int out_size, void* d_ws, size_t ws_size,
                              hipStream_t stream) {
  const void*  z   = d_in[0];                 // bool (B,T,CIN) - int32 0/1 (detected)
  const void*  h0  = d_in[1];                 // bool (B,CH)
  const float* Ain = (const float*)d_in[2];   // (CH,CIN) f32
  const float* Ah  = (const float*)d_in[3];   // (CH,CH)  f32
  uint32_t* out = (uint32_t*)d_out;           // int32 0/1

  char* ws = (char*)d_ws;
  // ws layout (bytes): [0] mode | [256] idx_in 48K | [49408] idx_h 48K |
  //                    [98560] in_orb 4MiB | [4292864] hbits 4MiB  (total ~8.1 MiB)
  uint32_t* modep = (uint32_t*)(ws);
  uint32_t* idxin = (uint32_t*)(ws + 256);
  uint32_t* idxh  = (uint32_t*)(ws + 256 + 49152);
  uint32_t* inorb = (uint32_t*)(ws + 98560);
  uint32_t* hbits = (uint32_t*)(ws + 98560 + 4194304);

  detect_kernel <<<1,    256,  0, stream>>>((const uint32_t*)z, modep);
  extract_kernel<<<2048, 256,  0, stream>>>(Ain, Ah, idxin, idxh);
  inor_kernel   <<<T_,   1024, 0, stream>>>(z, idxin, modep, inorb);
  scan_kernel   <<<B_,   1024, 0, stream>>>(inorb, idxh, h0, modep, hbits);
  expand_kernel <<<B_ * T_, 1024, 0, stream>>>(z, hbits, modep, out);
}

// Round 3
// 960.377 us; speedup vs baseline: 1.2283x; 1.2283x over previous
//
#include <hip/hip_runtime.h>
#include <stdint.h>

#define B_   8
#define T_   1024
#define CIN_ 4096
#define CH_  4096

// ---------------- helpers ----------------

// per-byte nonzero -> 0x01, packed
__device__ __forceinline__ uint32_t bytes_nonzero01(uint32_t w) {
  uint32_t t = (w & 0x7F7F7F7Fu) + 0x7F7F7F7Fu;
  t = (t | w) & 0x80808080u;
  return t >> 7;
}

// load 4 consecutive boolean elements (elements idx4*4 .. idx4*4+3) from a
// buffer whose element size is es (1, 2 or 4 bytes); return packed bytes 0/1.
__device__ __forceinline__ uint32_t load4(const void* base, long idx4, int es) {
  if (es == 1) {
    uint32_t w = ((const uint32_t*)base)[idx4];
    return bytes_nonzero01(w);
  } else if (es == 2) {
    uint32_t w0 = ((const uint32_t*)base)[idx4 * 2];
    uint32_t w1 = ((const uint32_t*)base)[idx4 * 2 + 1];
    uint32_t r = 0;
    r |= ((w0 & 0xFFFFu) != 0u) ? 0x00000001u : 0u;
    r |= ((w0 >> 16)     != 0u) ? 0x00000100u : 0u;
    r |= ((w1 & 0xFFFFu) != 0u) ? 0x00010000u : 0u;
    r |= ((w1 >> 16)     != 0u) ? 0x01000000u : 0u;
    return r;
  } else {
    uint4 w = ((const uint4*)base)[idx4];
    uint32_t r = 0;
    r |= (w.x != 0u) ? 0x00000001u : 0u;
    r |= (w.y != 0u) ? 0x00000100u : 0u;
    r |= (w.z != 0u) ? 0x00010000u : 0u;
    r |= (w.w != 0u) ? 0x01000000u : 0u;
    return r;
  }
}

// expand 4 packed 0/1 bytes into 4 int32 0/1
__device__ __forceinline__ uint4 expand01(uint32_t v4) {
  uint4 r = { v4 & 1u, (v4 >> 8) & 1u, (v4 >> 16) & 1u, (v4 >> 24) & 1u };
  return r;
}

// ---------------- kernel 0: encoding detection ----------------
// Round-1 evidence: absmax = float_bits(1.0)-1 => harness uses int32 for bool
// arrays; detect resolves mode=4 via the sW branch. Kept for robustness.
__global__ __launch_bounds__(256) void detect_kernel(const uint32_t* __restrict__ z,
                                                     uint32_t* __restrict__ modep) {
  __shared__ int sB, sH, sW, sL;
  const int n = threadIdx.x;
  if (n == 0) { sB = 1; sH = 1; sW = 1; sL = 0; }
  __syncthreads();
  int okB = 1, okH = 1, okW = 1, low = 0;
  for (int k = 0; k < 16; ++k) {
    uint32_t w = z[n + 256 * k];
    if ((w & 0xFEFEFEFEu) != 0u) okB = 0;                    // bytes in {0,1}?
    uint32_t lo = w & 0xFFFFu, hi = w >> 16;
    if (!((lo == 0u || lo == 0x3F80u) && (hi == 0u || hi == 0x3F80u))) okH = 0;
    if (!(w == 0u || w == 1u)) okW = 0;                      // words in {0,1}?
    if (lo != 0u) low = 1;                                   // f32 has low half 0
  }
  if (!okB) atomicAnd(&sB, 0);
  if (!okH) atomicAnd(&sH, 0);
  if (!okW) atomicAnd(&sW, 0);
  if (low)  atomicOr(&sL, 1);
  __syncthreads();
  if (n == 0) {
    uint32_t mode;
    if (sW)      mode = 4;              // int32 0/1
    else if (sB) mode = 1;              // uint8 bool
    else if (sH) mode = sL ? 2 : 4;     // bf16 : float32
    else         mode = 1;              // fallback (shouldn't happen)
    modep[0] = mode;
  }
}

// ---------------- kernel 1: fan-in index extraction ----------------
// One wave per row; rows 0..4095 = A_input, 4096..8191 = A_hidden.
__global__ __launch_bounds__(256) void extract_kernel(const float* __restrict__ Ain,
                                                      const float* __restrict__ Ah,
                                                      uint32_t* __restrict__ idxin,
                                                      uint32_t* __restrict__ idxh) {
  const int wave = threadIdx.x >> 6;
  const int lane = threadIdx.x & 63;
  const int row  = blockIdx.x * 4 + wave;   // 0..8191
  const float* A;
  uint32_t* outp;
  if (row < 4096) { A = Ain + (long)row * 4096;          outp = idxin + row * 3; }
  else            { A = Ah  + (long)(row - 4096) * 4096; outp = idxh + (row - 4096) * 3; }
  int count = 0;
  for (int it = 0; it < 64; ++it) {
    float v = A[it * 64 + lane];
    unsigned long long m = __ballot(v != 0.0f);
    if (m) {
      if (v != 0.0f) {
        int pos = count + (int)__popcll(m & ((1ull << lane) - 1ull));
        if (pos < 3) outp[pos] = (uint32_t)(it * 64 + lane);
      }
      count += (int)__popcll(m);
      if (count >= 3) break;   // exactly 3 per row; wave-uniform break
    }
  }
}

// ---------------- kernel 2: input-OR precompute + z-copy to out ----------------
// in_orb byte [t][i] = bit b set iff (z[b,t,c0]|z[b,t,c1]|z[b,t,c2]).
// Also writes the z-half of out (int32 0/1) — z is only read ONCE total.
__global__ __launch_bounds__(1024) void inor_kernel(const void* __restrict__ z,
                                                    const uint32_t* __restrict__ idxin,
                                                    const uint32_t* __restrict__ modep,
                                                    uint32_t* __restrict__ in_orb,
                                                    uint32_t* __restrict__ out) {
  const int t = blockIdx.x;
  const int n = threadIdx.x;
  const int es = (int)modep[0];
  __shared__ __align__(16) unsigned char zp[4096];   // batch-packed z row
  uint32_t acc = 0;
  #pragma unroll
  for (int b = 0; b < B_; ++b) {
    uint32_t v4 = load4(z, ((long)b * T_ + t) * 1024 + n, es);
    acc |= v4 << b;
    ((uint4*)(out + ((long)b * T_ + t) * 8192))[n] = expand01(v4);
  }
  ((uint32_t*)zp)[n] = acc;
  __syncthreads();
  const uint4* ip = (const uint4*)(idxin + n * 12);  // indices for neurons 4n..4n+3
  uint4 q0 = ip[0], q1 = ip[1], q2 = ip[2];
  uint32_t r0 = (uint32_t)zp[q0.x] | zp[q0.y] | zp[q0.z];
  uint32_t r1 = (uint32_t)zp[q0.w] | zp[q1.x] | zp[q1.y];
  uint32_t r2 = (uint32_t)zp[q1.z] | zp[q1.w] | zp[q2.x];
  uint32_t r3 = (uint32_t)zp[q2.y] | zp[q2.z] | zp[q2.w];
  in_orb[t * 1024 + n] = r0 | (r1 << 8) | (r2 << 16) | (r3 << 24);
}

// ---------------- kernel 3: sequential scan (the recurrence) ----------------
// 8 blocks, one per batch. h kept as 4096 bytes in double-buffered LDS.
// Writes the h-half of out directly (idle VMEM pipe; DS pipe is the bottleneck).
__global__ __launch_bounds__(1024) void scan_kernel(const uint32_t* __restrict__ in_orb,
                                                    const uint32_t* __restrict__ idxh,
                                                    const void* __restrict__ h0,
                                                    const uint32_t* __restrict__ modep,
                                                    uint32_t* __restrict__ out) {
  const int b = blockIdx.x;
  const int n = threadIdx.x;
  const int es = (int)modep[0];
  __shared__ __align__(16) unsigned char hbuf[2][4096];

  // fan-in indices for neurons 4n..4n+3 -> registers (loop-invariant)
  uint32_t d[4][3];
  {
    const uint4* p = (const uint4*)(idxh + n * 12);
    uint4 q0 = p[0], q1 = p[1], q2 = p[2];
    d[0][0] = q0.x; d[0][1] = q0.y; d[0][2] = q0.z;
    d[1][0] = q0.w; d[1][1] = q1.x; d[1][2] = q1.y;
    d[2][0] = q1.z; d[2][1] = q1.w; d[2][2] = q2.x;
    d[3][0] = q2.y; d[3][1] = q2.z; d[3][2] = q2.w;
  }

  // init h(-1) = h0[b]
  ((uint32_t*)hbuf[0])[n] = load4(h0, (long)b * 1024 + n, es);
  __syncthreads();

  uint32_t* outh = out + (long)b * T_ * 8192 + 4096;  // h-half of out for batch b

  int p = 0;
  uint32_t inw = in_orb[n];   // t = 0 (prefetched)
  for (int t = 0; t < T_; ++t) {
    uint32_t inw_next = (t + 1 < T_) ? in_orb[(t + 1) * 1024 + n] : 0u;
    const unsigned char* hc = &hbuf[p][0];
    unsigned char* hn = &hbuf[p ^ 1][0];

    uint32_t mask = (inw >> b) & 0x01010101u;   // input-OR bits for my 4 neurons
    uint32_t out4 = 0;
    if (mask) {  // early-out: ~61% of masks per neuron are 0
      if (mask & 0x00000001u) {
        uint32_t v = (uint32_t)hc[d[0][0]] | hc[d[0][1]] | hc[d[0][2]];
        out4 |= v;
      }
      if (mask & 0x00000100u) {
        uint32_t v = (uint32_t)hc[d[1][0]] | hc[d[1][1]] | hc[d[1][2]];
        out4 |= v << 8;
      }
      if (mask & 0x00010000u) {
        uint32_t v = (uint32_t)hc[d[2][0]] | hc[d[2][1]] | hc[d[2][2]];
        out4 |= v << 16;
      }
      if (mask & 0x01000000u) {
        uint32_t v = (uint32_t)hc[d[3][0]] | hc[d[3][1]] | hc[d[3][2]];
        out4 |= v << 24;
      }
    }
    ((uint32_t*)hn)[n] = out4;   // bytes 0/1
    // direct h output: 4 int32 per thread, coalesced uint4 (fire-and-forget)
    ((uint4*)(outh + (long)t * 8192))[n] = expand01(out4);
    __syncthreads();

    inw = inw_next;
    p ^= 1;
  }
}

// ---------------- launch ----------------
extern "C" void kernel_launch(void* const* d_in, const int* in_sizes, int n_in,
                              void* d_out, int out_size, void* d_ws, size_t ws_size,
                              hipStream_t stream) {
  const void*  z   = d_in[0];                 // bool (B,T,CIN) - int32 0/1 (detected)
  const void*  h0  = d_in[1];                 // bool (B,CH)
  const float* Ain = (const float*)d_in[2];   // (CH,CIN) f32
  const float* Ah  = (const float*)d_in[3];   // (CH,CH)  f32
  uint32_t* out = (uint32_t*)d_out;           // int32 0/1

  char* ws = (char*)d_ws;
  // ws layout (bytes): [0] mode | [256] idx_in 48K | [49408] idx_h 48K |
  //                    [98560] in_orb 4MiB   (total ~4.3 MiB)
  uint32_t* modep = (uint32_t*)(ws);
  uint32_t* idxin = (uint32_t*)(ws + 256);
  uint32_t* idxh  = (uint32_t*)(ws + 256 + 49152);
  uint32_t* inorb = (uint32_t*)(ws + 98560);

  detect_kernel <<<1,    256,  0, stream>>>((const uint32_t*)z, modep);
  extract_kernel<<<2048, 256,  0, stream>>>(Ain, Ah, idxin, idxh);
  inor_kernel   <<<T_,   1024, 0, stream>>>(z, idxin, modep, inorb, out);
  scan_kernel   <<<B_,   1024, 0, stream>>>(inorb, idxh, h0, modep, out);
}

// Round 4
// 954.926 us; speedup vs baseline: 1.2354x; 1.0057x over previous
//
#include <hip/hip_runtime.h>
#include <stdint.h>

#define B_   8
#define T_   1024
#define CIN_ 4096
#define CH_  4096

// ---------------- helpers ----------------

// per-byte nonzero -> 0x01, packed
__device__ __forceinline__ uint32_t bytes_nonzero01(uint32_t w) {
  uint32_t t = (w & 0x7F7F7F7Fu) + 0x7F7F7F7Fu;
  t = (t | w) & 0x80808080u;
  return t >> 7;
}

// load 4 consecutive boolean elements (elements idx4*4 .. idx4*4+3) from a
// buffer whose element size is es (1, 2 or 4 bytes); return packed bytes 0/1.
__device__ __forceinline__ uint32_t load4(const void* base, long idx4, int es) {
  if (es == 1) {
    uint32_t w = ((const uint32_t*)base)[idx4];
    return bytes_nonzero01(w);
  } else if (es == 2) {
    uint32_t w0 = ((const uint32_t*)base)[idx4 * 2];
    uint32_t w1 = ((const uint32_t*)base)[idx4 * 2 + 1];
    uint32_t r = 0;
    r |= ((w0 & 0xFFFFu) != 0u) ? 0x00000001u : 0u;
    r |= ((w0 >> 16)     != 0u) ? 0x00000100u : 0u;
    r |= ((w1 & 0xFFFFu) != 0u) ? 0x00010000u : 0u;
    r |= ((w1 >> 16)     != 0u) ? 0x01000000u : 0u;
    return r;
  } else {
    uint4 w = ((const uint4*)base)[idx4];
    uint32_t r = 0;
    r |= (w.x != 0u) ? 0x00000001u : 0u;
    r |= (w.y != 0u) ? 0x00000100u : 0u;
    r |= (w.z != 0u) ? 0x00010000u : 0u;
    r |= (w.w != 0u) ? 0x01000000u : 0u;
    return r;
  }
}

// expand 4 packed 0/1 bytes into 4 int32 0/1
__device__ __forceinline__ uint4 expand01(uint32_t v4) {
  uint4 r = { v4 & 1u, (v4 >> 8) & 1u, (v4 >> 16) & 1u, (v4 >> 24) & 1u };
  return r;
}

// ---------------- kernel 0: encoding detection ----------------
// Round-1 evidence: absmax = float_bits(1.0)-1 => harness uses int32 for bool
// arrays; detect resolves mode=4 via the sW branch. Kept for robustness.
__global__ __launch_bounds__(256) void detect_kernel(const uint32_t* __restrict__ z,
                                                     uint32_t* __restrict__ modep) {
  __shared__ int sB, sH, sW, sL;
  const int n = threadIdx.x;
  if (n == 0) { sB = 1; sH = 1; sW = 1; sL = 0; }
  __syncthreads();
  int okB = 1, okH = 1, okW = 1, low = 0;
  for (int k = 0; k < 16; ++k) {
    uint32_t w = z[n + 256 * k];
    if ((w & 0xFEFEFEFEu) != 0u) okB = 0;                    // bytes in {0,1}?
    uint32_t lo = w & 0xFFFFu, hi = w >> 16;
    if (!((lo == 0u || lo == 0x3F80u) && (hi == 0u || hi == 0x3F80u))) okH = 0;
    if (!(w == 0u || w == 1u)) okW = 0;                      // words in {0,1}?
    if (lo != 0u) low = 1;                                   // f32 has low half 0
  }
  if (!okB) atomicAnd(&sB, 0);
  if (!okH) atomicAnd(&sH, 0);
  if (!okW) atomicAnd(&sW, 0);
  if (low)  atomicOr(&sL, 1);
  __syncthreads();
  if (n == 0) {
    uint32_t mode;
    if (sW)      mode = 4;              // int32 0/1
    else if (sB) mode = 1;              // uint8 bool
    else if (sH) mode = sL ? 2 : 4;     // bf16 : float32
    else         mode = 1;              // fallback (shouldn't happen)
    modep[0] = mode;
  }
}

// ---------------- kernel 1: fan-in index extraction (rewritten) ----------------
// One wave per row. R3 version had a data-dependent early-break => ~48-deep
// serial dependent-load chain per wave (suspected source of the unattributed
// ~380 us). Now: full-row scan, 16 independent float4 loads (pipelined),
// LDS atomic slot counter (index order is irrelevant - consumers only OR).
__global__ __launch_bounds__(256) void extract_kernel(const float* __restrict__ Ain,
                                                      const float* __restrict__ Ah,
                                                      uint32_t* __restrict__ idxin,
                                                      uint32_t* __restrict__ idxh) {
  const int wave = threadIdx.x >> 6;
  const int lane = threadIdx.x & 63;
  const int row  = blockIdx.x * 4 + wave;   // 0..8191
  const float* A;
  uint32_t* outp;
  if (row < 4096) { A = Ain + (long)row * 4096;          outp = idxin + row * 3; }
  else            { A = Ah  + (long)(row - 4096) * 4096; outp = idxh + (row - 4096) * 3; }
  __shared__ int cnt[4];
  if (lane == 0) cnt[wave] = 0;
  __syncthreads();
  const float4* A4 = (const float4*)A;
  #pragma unroll
  for (int it = 0; it < 16; ++it) {
    float4 v = A4[it * 64 + lane];          // cols 4*(it*64+lane) .. +3
    int cbase = (it * 64 + lane) * 4;
    if (v.x != 0.0f) { int p = atomicAdd(&cnt[wave], 1); if (p < 3) outp[p] = cbase;     }
    if (v.y != 0.0f) { int p = atomicAdd(&cnt[wave], 1); if (p < 3) outp[p] = cbase + 1; }
    if (v.z != 0.0f) { int p = atomicAdd(&cnt[wave], 1); if (p < 3) outp[p] = cbase + 2; }
    if (v.w != 0.0f) { int p = atomicAdd(&cnt[wave], 1); if (p < 3) outp[p] = cbase + 3; }
  }
}

// ---------------- kernel 2: input-OR precompute + z-copy to out ----------------
// in_orb byte [t][i] = bit b set iff (z[b,t,c0]|z[b,t,c1]|z[b,t,c2]).
// Also writes the z-half of out (int32 0/1) — z is only read ONCE total.
__global__ __launch_bounds__(1024) void inor_kernel(const void* __restrict__ z,
                                                    const uint32_t* __restrict__ idxin,
                                                    const uint32_t* __restrict__ modep,
                                                    uint32_t* __restrict__ in_orb,
                                                    uint32_t* __restrict__ out) {
  const int t = blockIdx.x;
  const int n = threadIdx.x;
  const int es = (int)modep[0];
  __shared__ __align__(16) unsigned char zp[4096];   // batch-packed z row
  uint32_t acc = 0;
  #pragma unroll
  for (int b = 0; b < B_; ++b) {
    uint32_t v4 = load4(z, ((long)b * T_ + t) * 1024 + n, es);
    acc |= v4 << b;
    ((uint4*)(out + ((long)b * T_ + t) * 8192))[n] = expand01(v4);
  }
  ((uint32_t*)zp)[n] = acc;
  __syncthreads();
  const uint4* ip = (const uint4*)(idxin + n * 12);  // indices for neurons 4n..4n+3
  uint4 q0 = ip[0], q1 = ip[1], q2 = ip[2];
  uint32_t r0 = (uint32_t)zp[q0.x] | zp[q0.y] | zp[q0.z];
  uint32_t r1 = (uint32_t)zp[q0.w] | zp[q1.x] | zp[q1.y];
  uint32_t r2 = (uint32_t)zp[q1.z] | zp[q1.w] | zp[q2.x];
  uint32_t r3 = (uint32_t)zp[q2.y] | zp[q2.z] | zp[q2.w];
  in_orb[t * 1024 + n] = r0 | (r1 << 8) | (r2 << 16) | (r3 << 24);
}

// ---------------- kernel 3: sequential scan (the recurrence) ----------------
// 8 blocks, one per batch. h kept as 4096 bytes in double-buffered LDS.
// DS-pipe bound: 208 DS wave-ops/step + ~400 conflict cyc = ~1600 cyc/step.
// Writes the h-half of out directly (idle VMEM pipe).
__global__ __launch_bounds__(1024) void scan_kernel(const uint32_t* __restrict__ in_orb,
                                                    const uint32_t* __restrict__ idxh,
                                                    const void* __restrict__ h0,
                                                    const uint32_t* __restrict__ modep,
                                                    uint32_t* __restrict__ out) {
  const int b = blockIdx.x;
  const int n = threadIdx.x;
  const int es = (int)modep[0];
  __shared__ __align__(16) unsigned char hbuf[2][4096];

  // fan-in indices for neurons 4n..4n+3 -> registers (loop-invariant)
  uint32_t d[4][3];
  {
    const uint4* p = (const uint4*)(idxh + n * 12);
    uint4 q0 = p[0], q1 = p[1], q2 = p[2];
    d[0][0] = q0.x; d[0][1] = q0.y; d[0][2] = q0.z;
    d[1][0] = q0.w; d[1][1] = q1.x; d[1][2] = q1.y;
    d[2][0] = q1.z; d[2][1] = q1.w; d[2][2] = q2.x;
    d[3][0] = q2.y; d[3][1] = q2.z; d[3][2] = q2.w;
  }

  // init h(-1) = h0[b]
  ((uint32_t*)hbuf[0])[n] = load4(h0, (long)b * 1024 + n, es);
  __syncthreads();

  uint32_t* outh = out + (long)b * T_ * 8192 + 4096;  // h-half of out for batch b

  int p = 0;
  uint32_t inw = in_orb[n];   // t = 0 (prefetched)
  for (int t = 0; t < T_; ++t) {
    uint32_t inw_next = (t + 1 < T_) ? in_orb[(t + 1) * 1024 + n] : 0u;
    const unsigned char* hc = &hbuf[p][0];
    unsigned char* hn = &hbuf[p ^ 1][0];

    uint32_t mask = (inw >> b) & 0x01010101u;   // input-OR bits for my 4 neurons
    uint32_t out4 = 0;
    if (mask) {
      if (mask & 0x00000001u) {
        uint32_t v = (uint32_t)hc[d[0][0]] | hc[d[0][1]] | hc[d[0][2]];
        out4 |= v;
      }
      if (mask & 0x00000100u) {
        uint32_t v = (uint32_t)hc[d[1][0]] | hc[d[1][1]] | hc[d[1][2]];
        out4 |= v << 8;
      }
      if (mask & 0x00010000u) {
        uint32_t v = (uint32_t)hc[d[2][0]] | hc[d[2][1]] | hc[d[2][2]];
        out4 |= v << 16;
      }
      if (mask & 0x01000000u) {
        uint32_t v = (uint32_t)hc[d[3][0]] | hc[d[3][1]] | hc[d[3][2]];
        out4 |= v << 24;
      }
    }
    ((uint32_t*)hn)[n] = out4;   // bytes 0/1
    // direct h output: 4 int32 per thread, coalesced uint4 (fire-and-forget)
    ((uint4*)(outh + (long)t * 8192))[n] = expand01(out4);
    __syncthreads();

    inw = inw_next;
    p ^= 1;
  }
}

// ---------------- launch ----------------
extern "C" void kernel_launch(void* const* d_in, const int* in_sizes, int n_in,
                              void* d_out, int out_size, void* d_ws, size_t ws_size,
                              hipStream_t stream) {
  const void*  z   = d_in[0];                 // bool (B,T,CIN) - int32 0/1 (detected)
  const void*  h0  = d_in[1];                 // bool (B,CH)
  const float* Ain = (const float*)d_in[2];   // (CH,CIN) f32
  const float* Ah  = (const float*)d_in[3];   // (CH,CH)  f32
  uint32_t* out = (uint32_t*)d_out;           // int32 0/1

  char* ws = (char*)d_ws;
  // ws layout (bytes): [0] mode | [256] idx_in 48K | [49408] idx_h 48K |
  //                    [98560] in_orb 4MiB   (total ~4.3 MiB)
  uint32_t* modep = (uint32_t*)(ws);
  uint32_t* idxin = (uint32_t*)(ws + 256);
  uint32_t* idxh  = (uint32_t*)(ws + 256 + 49152);
  uint32_t* inorb = (uint32_t*)(ws + 98560);

  detect_kernel <<<1,    256,  0, stream>>>((const uint32_t*)z, modep);
  extract_kernel<<<2048, 256,  0, stream>>>(Ain, Ah, idxin, idxh);
  inor_kernel   <<<T_,   1024, 0, stream>>>(z, idxin, modep, inorb, out);
  scan_kernel   <<<B_,   1024, 0, stream>>>(inorb, idxh, h0, modep, out);
}